// Round 4
// baseline (212.276 us; speedup 1.0000x reference)
//
#include <hip/hip_runtime.h>

#define N 4096
#define CIN 64
#define NB 2

typedef unsigned short u16;
typedef short bf16x8 __attribute__((ext_vector_type(8)));
typedef float f32x4 __attribute__((ext_vector_type(4)));

// workspace layout (float offsets). OFF_V region holds bf16 (u16) V.
// OFF_QK holds qkj[n][8] = q[n] . kj
#define OFF_QT 0
#define OFF_KT (OFF_QT + NB*N*8)
#define OFF_JT (OFF_KT + NB*N*8)
#define OFF_V  (OFF_JT + NB*N*8)
#define OFF_QK (OFF_V + NB*CIN*N)
#define OFF_MX (OFF_QK + NB*N*8)
#define OFF_SC (OFF_MX + NB*N)

__device__ __forceinline__ u16 f2bf(float f) {
    union { float f; unsigned u; } v; v.f = f;
    unsigned r = (v.u + 0x7fffu + ((v.u >> 16) & 1u)) >> 16;  // RNE
    return (u16)r;
}

// ---- prep: 512-thread blocks, c-split across halves (round-3, verified) ----
__global__ __launch_bounds__(512, 4) void prep(
        const float* __restrict__ x,
        const float* __restrict__ wq, const float* __restrict__ bq,
        const float* __restrict__ wk, const float* __restrict__ bk,
        const float* __restrict__ wj, const float* __restrict__ bj,
        const float* __restrict__ wv, const float* __restrict__ bv,
        float* __restrict__ ws, u16* __restrict__ vbf, float* __restrict__ out) {
    __shared__ union {
        float qkj[3][256];
        float accv[256][8];
    } sh;
    const int t    = threadIdx.x;
    const int tn   = t & 255;
    const int half = t >> 8;               // c-half: 0 -> c 0..31, 1 -> c 32..63
    const int y    = blockIdx.y;
    const int b    = blockIdx.z;
    const int n    = blockIdx.x * 256 + tn;
    const float* xb = x + (size_t)b * CIN * N + n;
    const int c0base = half * 32;

    if (y < 8) {
        int cq = y;
        int d = n & 15, w = (n >> 4) & 15, h = n >> 8;
        int owl = (w > 0) ? -16 : 0,  owh = (w < 15) ? 16 : 0;
        int ohl = (h > 0) ? -256 : 0, ohh = (h < 15) ? 256 : 0;
        int odl = (d > 0) ? -1 : 0,   odh = (d < 15) ? 1 : 0;
        float mwl = (w > 0) ? 1.f : 0.f, mwh = (w < 15) ? 1.f : 0.f;
        float mhl = (h > 0) ? 1.f : 0.f, mhh = (h < 15) ? 1.f : 0.f;
        float mdl = (d > 0) ? 1.f : 0.f, mdh = (d < 15) ? 1.f : 0.f;
        float q = half ? 0.f : bq[cq];
        float k = half ? 0.f : bk[cq];
        float j = half ? 0.f : bj[cq];
        for (int c0i = 0; c0i < 32; c0i += 8) {
            const int c0 = c0base + c0i;
            float xc[8], xwl[8], xwh[8], xhl[8], xhh[8], xdl[8], xdh[8];
#pragma unroll
            for (int u = 0; u < 8; ++u) {       // 56 independent loads in flight
                const float* p = xb + (size_t)(c0 + u) * N;
                xc[u]  = p[0];
                xwl[u] = p[owl]; xwh[u] = p[owh];
                xhl[u] = p[ohl]; xhh[u] = p[ohh];
                xdl[u] = p[odl]; xdh[u] = p[odh];
            }
#pragma unroll
            for (int u = 0; u < 8; ++u) {
                int c = c0 + u;
                const float* wqr = wq + (cq * CIN + c) * 3;
                const float* wkr = wk + (cq * CIN + c) * 3;
                const float* wjr = wj + (cq * CIN + c) * 3;
                q += wqr[0] * (xwl[u] * mwl) + wqr[1] * xc[u] + wqr[2] * (xwh[u] * mwh);
                k += wkr[0] * (xhl[u] * mhl) + wkr[1] * xc[u] + wkr[2] * (xhh[u] * mhh);
                j += wjr[0] * (xdl[u] * mdl) + wjr[1] * xc[u] + wjr[2] * (xdh[u] * mdh);
            }
        }
        if (half) { sh.qkj[0][tn] = q; sh.qkj[1][tn] = k; sh.qkj[2][tn] = j; }
        __syncthreads();
        if (!half) {
            q += sh.qkj[0][tn]; k += sh.qkj[1][tn]; j += sh.qkj[2][tn];
            size_t base = (size_t)(b * N + n) * 8 + cq;
            ws[OFF_QT + base] = q;
            ws[OFF_KT + base] = k;
            ws[OFF_JT + base] = j;
        }
    } else {
        int yy = y - 8;
        int co0 = yy * 8;
        float acc[8];
#pragma unroll
        for (int i = 0; i < 8; ++i) acc[i] = half ? 0.f : bv[co0 + i];
        for (int c0i = 0; c0i < 32; c0i += 8) {
            const int c0 = c0base + c0i;
            float xv[8];
#pragma unroll
            for (int u = 0; u < 8; ++u) xv[u] = xb[(size_t)(c0 + u) * N];
#pragma unroll
            for (int u = 0; u < 8; ++u)
#pragma unroll
                for (int i = 0; i < 8; ++i)
                    acc[i] += wv[(co0 + i) * CIN + c0 + u] * xv[u];
            if ((c0 >> 3) == yy) {               // owning half copies out = x
#pragma unroll
                for (int u = 0; u < 8; ++u)
                    out[(size_t)(b * CIN + c0 + u) * N + n] = xv[u];
            }
        }
        if (half) {
#pragma unroll
            for (int i = 0; i < 8; ++i) sh.accv[tn][i] = acc[i];
        }
        __syncthreads();
        if (!half) {
#pragma unroll
            for (int i = 0; i < 8; ++i)
                vbf[(size_t)(b * CIN + co0 + i) * N + n] = f2bf(acc[i] + sh.accv[tn][i]);
        }
    }
}

// ---- kjqkj: per-block recompute kj = K J^T (LDS), then qkj[m] = q[m].kj -----
// grid (16, 2) block 256 (round-0 verified kernel, unchanged).
__global__ __launch_bounds__(256) void kjqkj(const float* __restrict__ ws_in,
                                             float* __restrict__ ws) {
    __shared__ float kjpart[4][64];
    __shared__ float kjs[64];
    const int t = threadIdx.x, lane = t & 63, wid = t >> 6;
    const int b = blockIdx.y;
    const float* ktb = ws_in + OFF_KT + (size_t)b * N * 8;
    const float* jtb = ws_in + OFF_JT + (size_t)b * N * 8;
    const float* qtb = ws_in + OFF_QT + (size_t)b * N * 8;

    float acc[64];
#pragma unroll
    for (int i = 0; i < 64; ++i) acc[i] = 0.f;
    for (int i = 0; i < 16; ++i) {
        int nn = i * 256 + t;
        const float4* kt = (const float4*)(ktb + (size_t)nn * 8);
        const float4* jt = (const float4*)(jtb + (size_t)nn * 8);
        float4 ka = kt[0], kb = kt[1], ja = jt[0], jb = jt[1];
        float kv[8] = {ka.x, ka.y, ka.z, ka.w, kb.x, kb.y, kb.z, kb.w};
        float jv[8] = {ja.x, ja.y, ja.z, ja.w, jb.x, jb.y, jb.z, jb.w};
#pragma unroll
        for (int c = 0; c < 8; ++c)
#pragma unroll
            for (int dd = 0; dd < 8; ++dd) acc[c * 8 + dd] += kv[c] * jv[dd];
    }
#pragma unroll
    for (int s = 32; s >= 1; s >>= 1)
#pragma unroll
        for (int i = 0; i < 64; ++i) acc[i] += __shfl_down(acc[i], s, 64);
    if (lane == 0) {
#pragma unroll
        for (int i = 0; i < 64; ++i) kjpart[wid][i] = acc[i];
    }
    __syncthreads();
    if (t < 64) kjs[t] = kjpart[0][t] + kjpart[1][t] + kjpart[2][t] + kjpart[3][t];
    __syncthreads();

    float kjr[64];
#pragma unroll
    for (int i = 0; i < 64; ++i) kjr[i] = kjs[i];   // LDS broadcast reads
    int m = blockIdx.x * 256 + t;
    const float4* qt = (const float4*)(qtb + (size_t)m * 8);
    float4 qa = qt[0], qb = qt[1];
    float qv[8] = {qa.x, qa.y, qa.z, qa.w, qb.x, qb.y, qb.z, qb.w};
    float o[8];
#pragma unroll
    for (int dd = 0; dd < 8; ++dd) {
        float a = 0.f;
#pragma unroll
        for (int c = 0; c < 8; ++c) a += qv[c] * kjr[c * 8 + dd];
        o[dd] = a;
    }
    float4* dst = (float4*)(ws + OFF_QK + (size_t)(b * N + m) * 8);
    dst[0] = make_float4(o[0], o[1], o[2], o[3]);
    dst[1] = make_float4(o[4], o[5], o[6], o[7]);
}

// ---- pass1: two-phase row softmax stats with stored scores -----------------
// grid 1024, block 512 (8 waves = 2 row-groups x 4 m-quarters). Block owns
// 8 rows. Wave: 4 rows x 16 m-iters, scores kept in regs (a[4][16]).
// Phase 1: pure fmax tree (no exp). Phase 2: 64 INDEPENDENT exps + tree sum.
// Kills the online-softmax serial chain (round-3 statsB: 57us, VALUBusy 42%).
__global__ __launch_bounds__(512, 4) void pass1(const float* __restrict__ ws,
                                                float* __restrict__ mx_o, float* __restrict__ sc_o,
                                                const float* __restrict__ gamma) {
    __shared__ float smx[4][8];     // [m-quarter][row-in-block]
    __shared__ float ssum[4][8];
    const int t = threadIdx.x, lane = t & 63, wid = t >> 6;
    const int rowgrp = wid & 1;     // which 4 rows of the block's 8
    const int mq     = wid >> 1;    // m-quarter (1024 m's each)
    const int R0 = blockIdx.x * 8;  // global row base (b*N+n)
    const int b  = R0 >> 12;
    const int r0 = R0 + rowgrp * 4;
    const float* ktb = ws + OFF_KT + (size_t)b * N * 8;

    float4 qa[4], qb[4];
#pragma unroll
    for (int rr = 0; rr < 4; ++rr) {
        const float4* q4 = (const float4*)(ws + OFF_QK + (size_t)(r0 + rr) * 8);
        qa[rr] = q4[0]; qb[rr] = q4[1];
    }

    float as[4][16];                // scores, kept in registers
#pragma unroll 4
    for (int i = 0; i < 16; ++i) {
        const int m = mq * 1024 + i * 64 + lane;
        const float4* kk4 = (const float4*)(ktb + (size_t)m * 8);
        float4 ka = kk4[0], kb2 = kk4[1];
#pragma unroll
        for (int rr = 0; rr < 4; ++rr)
            as[rr][i] = qa[rr].x * ka.x + qa[rr].y * ka.y + qa[rr].z * ka.z + qa[rr].w * ka.w
                      + qb[rr].x * kb2.x + qb[rr].y * kb2.y + qb[rr].z * kb2.z + qb[rr].w * kb2.w;
    }

    // lane-local max (tree), then 6-step wave max
    float mx[4];
#pragma unroll
    for (int rr = 0; rr < 4; ++rr) {
        float m01 = fmaxf(fmaxf(as[rr][0], as[rr][1]), fmaxf(as[rr][2], as[rr][3]));
        float m23 = fmaxf(fmaxf(as[rr][4], as[rr][5]), fmaxf(as[rr][6], as[rr][7]));
        float m45 = fmaxf(fmaxf(as[rr][8], as[rr][9]), fmaxf(as[rr][10], as[rr][11]));
        float m67 = fmaxf(fmaxf(as[rr][12], as[rr][13]), fmaxf(as[rr][14], as[rr][15]));
        mx[rr] = fmaxf(fmaxf(m01, m23), fmaxf(m45, m67));
    }
#pragma unroll
    for (int s = 32; s >= 1; s >>= 1)
#pragma unroll
        for (int rr = 0; rr < 4; ++rr)
            mx[rr] = fmaxf(mx[rr], __shfl_xor(mx[rr], s, 64));
    if (lane == 0) {
#pragma unroll
        for (int rr = 0; rr < 4; ++rr) smx[mq][rowgrp * 4 + rr] = mx[rr];
    }
    __syncthreads();
    float gm[4];
#pragma unroll
    for (int rr = 0; rr < 4; ++rr) {
        const int ri = rowgrp * 4 + rr;
        gm[rr] = fmaxf(fmaxf(smx[0][ri], smx[1][ri]), fmaxf(smx[2][ri], smx[3][ri]));
    }

    // 64 independent exps per thread + tree sum
    float sm[4];
#pragma unroll
    for (int rr = 0; rr < 4; ++rr) {
        float s0 = __expf(as[rr][0] - gm[rr])  + __expf(as[rr][1] - gm[rr])
                 + __expf(as[rr][2] - gm[rr])  + __expf(as[rr][3] - gm[rr]);
        float s1 = __expf(as[rr][4] - gm[rr])  + __expf(as[rr][5] - gm[rr])
                 + __expf(as[rr][6] - gm[rr])  + __expf(as[rr][7] - gm[rr]);
        float s2 = __expf(as[rr][8] - gm[rr])  + __expf(as[rr][9] - gm[rr])
                 + __expf(as[rr][10] - gm[rr]) + __expf(as[rr][11] - gm[rr]);
        float s3 = __expf(as[rr][12] - gm[rr]) + __expf(as[rr][13] - gm[rr])
                 + __expf(as[rr][14] - gm[rr]) + __expf(as[rr][15] - gm[rr]);
        sm[rr] = (s0 + s1) + (s2 + s3);
    }
#pragma unroll
    for (int s = 32; s >= 1; s >>= 1)
#pragma unroll
        for (int rr = 0; rr < 4; ++rr)
            sm[rr] += __shfl_xor(sm[rr], s, 64);
    if (lane == 0) {
#pragma unroll
        for (int rr = 0; rr < 4; ++rr) ssum[mq][rowgrp * 4 + rr] = sm[rr];
    }
    __syncthreads();
    if (t < 8) {
        float g  = fmaxf(fmaxf(smx[0][t], smx[1][t]), fmaxf(smx[2][t], smx[3][t]));
        float tt = (ssum[0][t] + ssum[1][t]) + (ssum[2][t] + ssum[3][t]);
        mx_o[R0 + t] = g;
        sc_o[R0 + t] = gamma[0] / tt;
    }
}

// ---- pass2: out += V_bf16 . (sc*exp(qkj[n].k[m]-mx))_bf16 via MFMA ----------
// grid (64, 8, 2) block 256 (verified round-0 kernel, unchanged).
__global__ __launch_bounds__(256) void pass2(const float* __restrict__ ws,
                                             const u16* __restrict__ vbf,
                                             float* __restrict__ out) {
    __shared__ u16 Pt[64][72];      // P' tile: [m][n]  (B-frag: B[k=n][col=m])
    __shared__ u16 Vt[64][72];      // V tile:  [c][n]  (A-frag: A[row=c][k=n])
    __shared__ float ks[64][8];     // k for this m-tile
    const int t  = threadIdx.x;
    const int b  = blockIdx.z;
    const int m0 = blockIdx.x * 64;
    const int ns = blockIdx.y;
    const float* qkT = ws + OFF_QK + (size_t)b * N * 8;
    const float* ktb = ws + OFF_KT + (size_t)b * N * 8;
    const float* mxv = ws + OFF_MX + (size_t)b * N;
    const float* scv = ws + OFF_SC + (size_t)b * N;
    const u16*   vb  = vbf + (size_t)b * CIN * N;

    if (t < 128) ((float4*)ks)[t] = ((const float4*)(ktb + (size_t)m0 * 8))[t];

    const int lane = t & 63;
    const int wid  = t >> 6;        // wave id -> m-subtile
    const int l16  = lane & 15;
    const int lq   = lane >> 4;     // lane quad -> k-octet / acc row group
    const int vc   = t >> 3;        // V staging row 0..31
    const int vseg = t & 7;

    f32x4 acc[4];
#pragma unroll
    for (int i = 0; i < 4; ++i) acc[i] = (f32x4){0.f, 0.f, 0.f, 0.f};

    for (int ch = 0; ch < 8; ++ch) {
        const int n0 = ns * 512 + ch * 64;
        const int n  = n0 + lane;
        const float4* q4 = (const float4*)(qkT + (size_t)n * 8);
        float4 qa = q4[0], qb = q4[1];
        float mxl = mxv[n], sl = scv[n];
        uint4 v0 = *(const uint4*)(vb + (size_t)vc        * N + n0 + vseg * 8);
        uint4 v1 = *(const uint4*)(vb + (size_t)(vc + 32) * N + n0 + vseg * 8);
        __syncthreads();            // prev chunk's MFMA reads done (chunk 0: ks staged)
#pragma unroll
        for (int r = 0; r < 16; ++r) {
            int mi = wid * 16 + r;
            float4 k0 = *(const float4*)&ks[mi][0];
            float4 k1 = *(const float4*)&ks[mi][4];
            float a = qa.x * k0.x + qa.y * k0.y + qa.z * k0.z + qa.w * k0.w
                    + qb.x * k1.x + qb.y * k1.y + qb.z * k1.z + qb.w * k1.w;
            Pt[mi][lane] = f2bf(__expf(a - mxl) * sl);  // gamma/rowsum folded in
        }
        *(uint4*)&Vt[vc][vseg * 8]      = v0;
        *(uint4*)&Vt[vc + 32][vseg * 8] = v1;
        __syncthreads();
#pragma unroll
        for (int kk = 0; kk < 2; ++kk) {
            int k0i = kk * 32 + lq * 8;
            bf16x8 bfrag = *(const bf16x8*)&Pt[wid * 16 + l16][k0i];
#pragma unroll
            for (int ct = 0; ct < 4; ++ct) {
                bf16x8 afrag = *(const bf16x8*)&Vt[ct * 16 + l16][k0i];
                acc[ct] = __builtin_amdgcn_mfma_f32_16x16x32_bf16(afrag, bfrag, acc[ct], 0, 0, 0);
            }
        }
    }
    float* ob = out + (size_t)b * CIN * N;
    const int mcol = m0 + wid * 16 + l16;
#pragma unroll
    for (int ct = 0; ct < 4; ++ct)
#pragma unroll
        for (int r = 0; r < 4; ++r) {
            int c = ct * 16 + lq * 4 + r;
            atomicAdd(&ob[(size_t)c * N + mcol], acc[ct][r]);
        }
}

extern "C" void kernel_launch(void* const* d_in, const int* in_sizes, int n_in,
                              void* d_out, int out_size, void* d_ws, size_t ws_size,
                              hipStream_t stream) {
    const float* x  = (const float*)d_in[0];
    const float* wq = (const float*)d_in[1];
    const float* bq = (const float*)d_in[2];
    const float* wk = (const float*)d_in[3];
    const float* bk = (const float*)d_in[4];
    const float* wj = (const float*)d_in[5];
    const float* bj = (const float*)d_in[6];
    const float* wv = (const float*)d_in[7];
    const float* bv = (const float*)d_in[8];
    const float* gamma = (const float*)d_in[9];
    float* ws  = (float*)d_ws;
    float* out = (float*)d_out;
    u16* vbf = (u16*)(ws + OFF_V);

    prep<<<dim3(16, 16, 2), 512, 0, stream>>>(x, wq, bq, wk, bk, wj, bj, wv, bv, ws, vbf, out);
    kjqkj<<<dim3(16, 2), 256, 0, stream>>>(ws, ws);
    pass1<<<1024, 512, 0, stream>>>(ws, ws + OFF_MX, ws + OFF_SC, gamma);
    pass2<<<dim3(64, 8, 2), 256, 0, stream>>>(ws, vbf, out);
}

// Round 5
// 155.727 us; speedup vs baseline: 1.3631x; 1.3631x over previous
//
#include <hip/hip_runtime.h>

#define N 4096
#define CIN 64
#define NB 2

typedef unsigned short u16;
typedef short bf16x8 __attribute__((ext_vector_type(8)));
typedef float f32x4 __attribute__((ext_vector_type(4)));

// workspace layout (float offsets). OFF_V region holds bf16 (u16) V.
// OFF_QK holds qkj[n][8] = q[n] . kj
#define OFF_QT 0
#define OFF_KT (OFF_QT + NB*N*8)
#define OFF_JT (OFF_KT + NB*N*8)
#define OFF_V  (OFF_JT + NB*N*8)
#define OFF_QK (OFF_V + NB*CIN*N)
#define OFF_MX (OFF_QK + NB*N*8)
#define OFF_SC (OFF_MX + NB*N)

__device__ __forceinline__ u16 f2bf(float f) {
    union { float f; unsigned u; } v; v.f = f;
    unsigned r = (v.u + 0x7fffu + ((v.u >> 16) & 1u)) >> 16;  // RNE
    return (u16)r;
}

// ---- prep: 512-thread blocks, c-split across halves (round-3, verified) ----
__global__ __launch_bounds__(512, 4) void prep(
        const float* __restrict__ x,
        const float* __restrict__ wq, const float* __restrict__ bq,
        const float* __restrict__ wk, const float* __restrict__ bk,
        const float* __restrict__ wj, const float* __restrict__ bj,
        const float* __restrict__ wv, const float* __restrict__ bv,
        float* __restrict__ ws, u16* __restrict__ vbf, float* __restrict__ out) {
    __shared__ union {
        float qkj[3][256];
        float accv[256][8];
    } sh;
    const int t    = threadIdx.x;
    const int tn   = t & 255;
    const int half = t >> 8;               // c-half: 0 -> c 0..31, 1 -> c 32..63
    const int y    = blockIdx.y;
    const int b    = blockIdx.z;
    const int n    = blockIdx.x * 256 + tn;
    const float* xb = x + (size_t)b * CIN * N + n;
    const int c0base = half * 32;

    if (y < 8) {
        int cq = y;
        int d = n & 15, w = (n >> 4) & 15, h = n >> 8;
        int owl = (w > 0) ? -16 : 0,  owh = (w < 15) ? 16 : 0;
        int ohl = (h > 0) ? -256 : 0, ohh = (h < 15) ? 256 : 0;
        int odl = (d > 0) ? -1 : 0,   odh = (d < 15) ? 1 : 0;
        float mwl = (w > 0) ? 1.f : 0.f, mwh = (w < 15) ? 1.f : 0.f;
        float mhl = (h > 0) ? 1.f : 0.f, mhh = (h < 15) ? 1.f : 0.f;
        float mdl = (d > 0) ? 1.f : 0.f, mdh = (d < 15) ? 1.f : 0.f;
        float q = half ? 0.f : bq[cq];
        float k = half ? 0.f : bk[cq];
        float j = half ? 0.f : bj[cq];
        for (int c0i = 0; c0i < 32; c0i += 8) {
            const int c0 = c0base + c0i;
            float xc[8], xwl[8], xwh[8], xhl[8], xhh[8], xdl[8], xdh[8];
#pragma unroll
            for (int u = 0; u < 8; ++u) {       // 56 independent loads in flight
                const float* p = xb + (size_t)(c0 + u) * N;
                xc[u]  = p[0];
                xwl[u] = p[owl]; xwh[u] = p[owh];
                xhl[u] = p[ohl]; xhh[u] = p[ohh];
                xdl[u] = p[odl]; xdh[u] = p[odh];
            }
#pragma unroll
            for (int u = 0; u < 8; ++u) {
                int c = c0 + u;
                const float* wqr = wq + (cq * CIN + c) * 3;
                const float* wkr = wk + (cq * CIN + c) * 3;
                const float* wjr = wj + (cq * CIN + c) * 3;
                q += wqr[0] * (xwl[u] * mwl) + wqr[1] * xc[u] + wqr[2] * (xwh[u] * mwh);
                k += wkr[0] * (xhl[u] * mhl) + wkr[1] * xc[u] + wkr[2] * (xhh[u] * mhh);
                j += wjr[0] * (xdl[u] * mdl) + wjr[1] * xc[u] + wjr[2] * (xdh[u] * mdh);
            }
        }
        if (half) { sh.qkj[0][tn] = q; sh.qkj[1][tn] = k; sh.qkj[2][tn] = j; }
        __syncthreads();
        if (!half) {
            q += sh.qkj[0][tn]; k += sh.qkj[1][tn]; j += sh.qkj[2][tn];
            size_t base = (size_t)(b * N + n) * 8 + cq;
            ws[OFF_QT + base] = q;
            ws[OFF_KT + base] = k;
            ws[OFF_JT + base] = j;
        }
    } else {
        int yy = y - 8;
        int co0 = yy * 8;
        float acc[8];
#pragma unroll
        for (int i = 0; i < 8; ++i) acc[i] = half ? 0.f : bv[co0 + i];
        for (int c0i = 0; c0i < 32; c0i += 8) {
            const int c0 = c0base + c0i;
            float xv[8];
#pragma unroll
            for (int u = 0; u < 8; ++u) xv[u] = xb[(size_t)(c0 + u) * N];
#pragma unroll
            for (int u = 0; u < 8; ++u)
#pragma unroll
                for (int i = 0; i < 8; ++i)
                    acc[i] += wv[(co0 + i) * CIN + c0 + u] * xv[u];
            if ((c0 >> 3) == yy) {               // owning half copies out = x
#pragma unroll
                for (int u = 0; u < 8; ++u)
                    out[(size_t)(b * CIN + c0 + u) * N + n] = xv[u];
            }
        }
        if (half) {
#pragma unroll
            for (int i = 0; i < 8; ++i) sh.accv[tn][i] = acc[i];
        }
        __syncthreads();
        if (!half) {
#pragma unroll
            for (int i = 0; i < 8; ++i)
                vbf[(size_t)(b * CIN + co0 + i) * N + n] = f2bf(acc[i] + sh.accv[tn][i]);
        }
    }
}

// ---- kjqkj: per-block recompute kj = K J^T (LDS), then qkj[m] = q[m].kj -----
// grid (16, 2) block 256 (round-0 verified kernel, unchanged).
__global__ __launch_bounds__(256) void kjqkj(const float* __restrict__ ws_in,
                                             float* __restrict__ ws) {
    __shared__ float kjpart[4][64];
    __shared__ float kjs[64];
    const int t = threadIdx.x, lane = t & 63, wid = t >> 6;
    const int b = blockIdx.y;
    const float* ktb = ws_in + OFF_KT + (size_t)b * N * 8;
    const float* jtb = ws_in + OFF_JT + (size_t)b * N * 8;
    const float* qtb = ws_in + OFF_QT + (size_t)b * N * 8;

    float acc[64];
#pragma unroll
    for (int i = 0; i < 64; ++i) acc[i] = 0.f;
    for (int i = 0; i < 16; ++i) {
        int nn = i * 256 + t;
        const float4* kt = (const float4*)(ktb + (size_t)nn * 8);
        const float4* jt = (const float4*)(jtb + (size_t)nn * 8);
        float4 ka = kt[0], kb = kt[1], ja = jt[0], jb = jt[1];
        float kv[8] = {ka.x, ka.y, ka.z, ka.w, kb.x, kb.y, kb.z, kb.w};
        float jv[8] = {ja.x, ja.y, ja.z, ja.w, jb.x, jb.y, jb.z, jb.w};
#pragma unroll
        for (int c = 0; c < 8; ++c)
#pragma unroll
            for (int dd = 0; dd < 8; ++dd) acc[c * 8 + dd] += kv[c] * jv[dd];
    }
#pragma unroll
    for (int s = 32; s >= 1; s >>= 1)
#pragma unroll
        for (int i = 0; i < 64; ++i) acc[i] += __shfl_down(acc[i], s, 64);
    if (lane == 0) {
#pragma unroll
        for (int i = 0; i < 64; ++i) kjpart[wid][i] = acc[i];
    }
    __syncthreads();
    if (t < 64) kjs[t] = kjpart[0][t] + kjpart[1][t] + kjpart[2][t] + kjpart[3][t];
    __syncthreads();

    float kjr[64];
#pragma unroll
    for (int i = 0; i < 64; ++i) kjr[i] = kjs[i];   // LDS broadcast reads
    int m = blockIdx.x * 256 + t;
    const float4* qt = (const float4*)(qtb + (size_t)m * 8);
    float4 qa = qt[0], qb = qt[1];
    float qv[8] = {qa.x, qa.y, qa.z, qa.w, qb.x, qb.y, qb.z, qb.w};
    float o[8];
#pragma unroll
    for (int dd = 0; dd < 8; ++dd) {
        float a = 0.f;
#pragma unroll
        for (int c = 0; c < 8; ++c) a += qv[c] * kjr[c * 8 + dd];
        o[dd] = a;
    }
    float4* dst = (float4*)(ws + OFF_QK + (size_t)(b * N + m) * 8);
    dst[0] = make_float4(o[0], o[1], o[2], o[3]);
    dst[1] = make_float4(o[4], o[5], o[6], o[7]);
}

// ---- pass1: two-phase row softmax stats, stored scores SIZED TO FIT REGS ---
// grid 2048, block 512 (8 waves = 8 m-eighths). Block owns 4 rows, covers all
// 4096 m: wave wid handles m in [wid*512, wid*512+512). as[4][8] = 32 VGPRs
// (round-4's as[4][16]=64 spilled -> 131MB scratch writes, VGPR_Count 56).
// Phase 1: pure fmax tree. Phase 2: 32 independent exps + tree sum.
__global__ __launch_bounds__(512, 4) void pass1(const float* __restrict__ ws,
                                                float* __restrict__ mx_o, float* __restrict__ sc_o,
                                                const float* __restrict__ gamma) {
    __shared__ float smx[8][4];     // [m-eighth wave][row]
    __shared__ float ssum[8][4];
    const int t = threadIdx.x, lane = t & 63, wid = t >> 6;
    const int r0 = blockIdx.x * 4;  // global row base (b*N+n)
    const int b  = r0 >> 12;
    const float* ktb = ws + OFF_KT + (size_t)b * N * 8;

    float4 qa[4], qb[4];
#pragma unroll
    for (int rr = 0; rr < 4; ++rr) {
        const float4* q4 = (const float4*)(ws + OFF_QK + (size_t)(r0 + rr) * 8);
        qa[rr] = q4[0]; qb[rr] = q4[1];
    }

    float as[4][8];                 // scores in registers (32 VGPRs)
#pragma unroll
    for (int i = 0; i < 8; ++i) {
        const int m = wid * 512 + i * 64 + lane;
        const float4* kk4 = (const float4*)(ktb + (size_t)m * 8);
        float4 ka = kk4[0], kb2 = kk4[1];
#pragma unroll
        for (int rr = 0; rr < 4; ++rr)
            as[rr][i] = qa[rr].x * ka.x + qa[rr].y * ka.y + qa[rr].z * ka.z + qa[rr].w * ka.w
                      + qb[rr].x * kb2.x + qb[rr].y * kb2.y + qb[rr].z * kb2.z + qb[rr].w * kb2.w;
    }

    // lane-local max (tree), then 6-step wave max
    float mx[4];
#pragma unroll
    for (int rr = 0; rr < 4; ++rr) {
        float m01 = fmaxf(fmaxf(as[rr][0], as[rr][1]), fmaxf(as[rr][2], as[rr][3]));
        float m23 = fmaxf(fmaxf(as[rr][4], as[rr][5]), fmaxf(as[rr][6], as[rr][7]));
        mx[rr] = fmaxf(m01, m23);
    }
#pragma unroll
    for (int s = 32; s >= 1; s >>= 1)
#pragma unroll
        for (int rr = 0; rr < 4; ++rr)
            mx[rr] = fmaxf(mx[rr], __shfl_xor(mx[rr], s, 64));
    if (lane == 0) {
#pragma unroll
        for (int rr = 0; rr < 4; ++rr) smx[wid][rr] = mx[rr];
    }
    __syncthreads();
    float gm[4];
#pragma unroll
    for (int rr = 0; rr < 4; ++rr) {
        float g0 = fmaxf(fmaxf(smx[0][rr], smx[1][rr]), fmaxf(smx[2][rr], smx[3][rr]));
        float g1 = fmaxf(fmaxf(smx[4][rr], smx[5][rr]), fmaxf(smx[6][rr], smx[7][rr]));
        gm[rr] = fmaxf(g0, g1);
    }

    // 32 independent exps per thread + tree sum
    float sm[4];
#pragma unroll
    for (int rr = 0; rr < 4; ++rr) {
        float s0 = __expf(as[rr][0] - gm[rr]) + __expf(as[rr][1] - gm[rr])
                 + __expf(as[rr][2] - gm[rr]) + __expf(as[rr][3] - gm[rr]);
        float s1 = __expf(as[rr][4] - gm[rr]) + __expf(as[rr][5] - gm[rr])
                 + __expf(as[rr][6] - gm[rr]) + __expf(as[rr][7] - gm[rr]);
        sm[rr] = s0 + s1;
    }
#pragma unroll
    for (int s = 32; s >= 1; s >>= 1)
#pragma unroll
        for (int rr = 0; rr < 4; ++rr)
            sm[rr] += __shfl_xor(sm[rr], s, 64);
    if (lane == 0) {
#pragma unroll
        for (int rr = 0; rr < 4; ++rr) ssum[wid][rr] = sm[rr];
    }
    __syncthreads();
    if (t < 4) {
        float g0 = fmaxf(fmaxf(smx[0][t], smx[1][t]), fmaxf(smx[2][t], smx[3][t]));
        float g1 = fmaxf(fmaxf(smx[4][t], smx[5][t]), fmaxf(smx[6][t], smx[7][t]));
        float g  = fmaxf(g0, g1);
        float tt = ((ssum[0][t] + ssum[1][t]) + (ssum[2][t] + ssum[3][t]))
                 + ((ssum[4][t] + ssum[5][t]) + (ssum[6][t] + ssum[7][t]));
        mx_o[r0 + t] = g;
        sc_o[r0 + t] = gamma[0] / tt;
    }
}

// ---- pass2: out += V_bf16 . (sc*exp(qkj[n].k[m]-mx))_bf16 via MFMA ----------
// grid (64, 8, 2) block 256 (verified round-0 kernel, unchanged).
__global__ __launch_bounds__(256) void pass2(const float* __restrict__ ws,
                                             const u16* __restrict__ vbf,
                                             float* __restrict__ out) {
    __shared__ u16 Pt[64][72];      // P' tile: [m][n]  (B-frag: B[k=n][col=m])
    __shared__ u16 Vt[64][72];      // V tile:  [c][n]  (A-frag: A[row=c][k=n])
    __shared__ float ks[64][8];     // k for this m-tile
    const int t  = threadIdx.x;
    const int b  = blockIdx.z;
    const int m0 = blockIdx.x * 64;
    const int ns = blockIdx.y;
    const float* qkT = ws + OFF_QK + (size_t)b * N * 8;
    const float* ktb = ws + OFF_KT + (size_t)b * N * 8;
    const float* mxv = ws + OFF_MX + (size_t)b * N;
    const float* scv = ws + OFF_SC + (size_t)b * N;
    const u16*   vb  = vbf + (size_t)b * CIN * N;

    if (t < 128) ((float4*)ks)[t] = ((const float4*)(ktb + (size_t)m0 * 8))[t];

    const int lane = t & 63;
    const int wid  = t >> 6;        // wave id -> m-subtile
    const int l16  = lane & 15;
    const int lq   = lane >> 4;     // lane quad -> k-octet / acc row group
    const int vc   = t >> 3;        // V staging row 0..31
    const int vseg = t & 7;

    f32x4 acc[4];
#pragma unroll
    for (int i = 0; i < 4; ++i) acc[i] = (f32x4){0.f, 0.f, 0.f, 0.f};

    for (int ch = 0; ch < 8; ++ch) {
        const int n0 = ns * 512 + ch * 64;
        const int n  = n0 + lane;
        const float4* q4 = (const float4*)(qkT + (size_t)n * 8);
        float4 qa = q4[0], qb = q4[1];
        float mxl = mxv[n], sl = scv[n];
        uint4 v0 = *(const uint4*)(vb + (size_t)vc        * N + n0 + vseg * 8);
        uint4 v1 = *(const uint4*)(vb + (size_t)(vc + 32) * N + n0 + vseg * 8);
        __syncthreads();            // prev chunk's MFMA reads done (chunk 0: ks staged)
#pragma unroll
        for (int r = 0; r < 16; ++r) {
            int mi = wid * 16 + r;
            float4 k0 = *(const float4*)&ks[mi][0];
            float4 k1 = *(const float4*)&ks[mi][4];
            float a = qa.x * k0.x + qa.y * k0.y + qa.z * k0.z + qa.w * k0.w
                    + qb.x * k1.x + qb.y * k1.y + qb.z * k1.z + qb.w * k1.w;
            Pt[mi][lane] = f2bf(__expf(a - mxl) * sl);  // gamma/rowsum folded in
        }
        *(uint4*)&Vt[vc][vseg * 8]      = v0;
        *(uint4*)&Vt[vc + 32][vseg * 8] = v1;
        __syncthreads();
#pragma unroll
        for (int kk = 0; kk < 2; ++kk) {
            int k0i = kk * 32 + lq * 8;
            bf16x8 bfrag = *(const bf16x8*)&Pt[wid * 16 + l16][k0i];
#pragma unroll
            for (int ct = 0; ct < 4; ++ct) {
                bf16x8 afrag = *(const bf16x8*)&Vt[ct * 16 + l16][k0i];
                acc[ct] = __builtin_amdgcn_mfma_f32_16x16x32_bf16(afrag, bfrag, acc[ct], 0, 0, 0);
            }
        }
    }
    float* ob = out + (size_t)b * CIN * N;
    const int mcol = m0 + wid * 16 + l16;
#pragma unroll
    for (int ct = 0; ct < 4; ++ct)
#pragma unroll
        for (int r = 0; r < 4; ++r) {
            int c = ct * 16 + lq * 4 + r;
            atomicAdd(&ob[(size_t)c * N + mcol], acc[ct][r]);
        }
}

extern "C" void kernel_launch(void* const* d_in, const int* in_sizes, int n_in,
                              void* d_out, int out_size, void* d_ws, size_t ws_size,
                              hipStream_t stream) {
    const float* x  = (const float*)d_in[0];
    const float* wq = (const float*)d_in[1];
    const float* bq = (const float*)d_in[2];
    const float* wk = (const float*)d_in[3];
    const float* bk = (const float*)d_in[4];
    const float* wj = (const float*)d_in[5];
    const float* bj = (const float*)d_in[6];
    const float* wv = (const float*)d_in[7];
    const float* bv = (const float*)d_in[8];
    const float* gamma = (const float*)d_in[9];
    float* ws  = (float*)d_ws;
    float* out = (float*)d_out;
    u16* vbf = (u16*)(ws + OFF_V);

    prep<<<dim3(16, 16, 2), 512, 0, stream>>>(x, wq, bq, wk, bk, wj, bj, wv, bv, ws, vbf, out);
    kjqkj<<<dim3(16, 2), 256, 0, stream>>>(ws, ws);
    pass1<<<2048, 512, 0, stream>>>(ws, ws + OFF_MX, ws + OFF_SC, gamma);
    pass2<<<dim3(64, 8, 2), 256, 0, stream>>>(ws, vbf, out);
}